// Round 3
// baseline (1569.218 us; speedup 1.0000x reference)
//
#include <hip/hip_runtime.h>
#include <hip/hip_bf16.h>

#define DM        1024
#define D_INNER   2048
#define NHEADS    32
#define HEADDIM   64
#define DSTATE    128
#define DCONV     4
#define CONV_DIM  (D_INNER + 2*DSTATE)            // 2304
#define D_IN_PROJ (2*D_INNER + 2*DSTATE + NHEADS) // 4384
#define BATCH     4
#define SEQ       1024
#define NROWS     (BATCH*SEQ)                     // 4096
#define EPSF      1e-5f

// ---------------- workspace layout (floats) ----------------
#define OFF_ZX   ((size_t)0)                        // [4096][4384]  zxbcdt
#define OFF_XBC  ((size_t)(NROWS)*D_IN_PROJ)        // [4096][2304]  conv+silu out
#define OFF_DT   (OFF_XBC + (size_t)NROWS*CONV_DIM) // [4096][32]
#define OFF_DA   (OFF_DT  + (size_t)NROWS*NHEADS)   // [4096][32]
#define OFF_Y    (OFF_DA  + (size_t)NROWS*NHEADS)   // [4096][2048]

__device__ __forceinline__ float sigmoidf_(float x) { return 1.f / (1.f + expf(-x)); }

// ---------------- K1/K5: fp32 tiled GEMM, C[M][N] = A[M][K] * B[N][K]^T ------
// 64x64 tile, K-step 16, 256 threads, 4x4 microtile per thread.
__global__ __launch_bounds__(256) void gemm_tn(const float* __restrict__ A,
                                               const float* __restrict__ Bw,
                                               float* __restrict__ C,
                                               int M, int N, int K) {
    const int tx = threadIdx.x & 15;   // 0..15 -> N
    const int ty = threadIdx.x >> 4;   // 0..15 -> M
    const int bm = blockIdx.y * 64;
    const int bn = blockIdx.x * 64;

    __shared__ float As[16][68];  // [k][m], stride 68: 272B rows stay 16B aligned
    __shared__ float Bs[16][68];  // [k][n]

    float acc[4][4] = {};

    for (int k0 = 0; k0 < K; k0 += 16) {
        #pragma unroll
        for (int i = 0; i < 4; ++i) {
            int idx = threadIdx.x + i * 256;   // 0..1023
            int m  = idx >> 4;
            int kk = idx & 15;
            As[kk][m] = A[(size_t)(bm + m) * K + k0 + kk];
            int e = bn + m;
            Bs[kk][m] = (e < N) ? Bw[(size_t)e * K + k0 + kk] : 0.f;
        }
        __syncthreads();
        #pragma unroll
        for (int kk = 0; kk < 16; ++kk) {
            float4 a = *(const float4*)&As[kk][ty * 4];
            float4 b = *(const float4*)&Bs[kk][tx * 4];
            float av[4] = {a.x, a.y, a.z, a.w};
            float bv[4] = {b.x, b.y, b.z, b.w};
            #pragma unroll
            for (int i = 0; i < 4; ++i)
                #pragma unroll
                for (int j = 0; j < 4; ++j)
                    acc[i][j] = fmaf(av[i], bv[j], acc[i][j]);
        }
        __syncthreads();
    }

    #pragma unroll
    for (int i = 0; i < 4; ++i) {
        int m = bm + ty * 4 + i;
        #pragma unroll
        for (int j = 0; j < 4; ++j) {
            int e = bn + tx * 4 + j;
            if (e < N) C[(size_t)m * N + e] = acc[i][j];
        }
    }
}

// ---------------- K2: causal depthwise conv(4) + silu ----------------
__global__ __launch_bounds__(256) void conv_silu(const float* __restrict__ zx,
                                                 const float* __restrict__ cw,
                                                 const float* __restrict__ cb,
                                                 float* __restrict__ xBC) {
    int idx = blockIdx.x * 256 + threadIdx.x;       // over NROWS*CONV_DIM
    if (idx >= NROWS * CONV_DIM) return;
    int c  = idx % CONV_DIM;
    int bl = idx / CONV_DIM;
    int b  = bl / SEQ;
    int l  = bl % SEQ;

    float w0 = cw[c * 4 + 0], w1 = cw[c * 4 + 1], w2 = cw[c * 4 + 2], w3 = cw[c * 4 + 3];
    const float* base = zx + (size_t)b * SEQ * D_IN_PROJ + D_INNER + c;

    float acc = cb[c];
    if (l >= 3) acc = fmaf(base[(size_t)(l - 3) * D_IN_PROJ], w0, acc);
    if (l >= 2) acc = fmaf(base[(size_t)(l - 2) * D_IN_PROJ], w1, acc);
    if (l >= 1) acc = fmaf(base[(size_t)(l - 1) * D_IN_PROJ], w2, acc);
    acc = fmaf(base[(size_t)l * D_IN_PROJ], w3, acc);

    xBC[idx] = acc * sigmoidf_(acc);
}

// ---------------- K2b: dt = softplus(dt_raw + bias), dA = exp(dt*A) ---------
__global__ __launch_bounds__(256) void dt_da(const float* __restrict__ zx,
                                             const float* __restrict__ dt_bias,
                                             const float* __restrict__ A_log,
                                             float* __restrict__ dt,
                                             float* __restrict__ dA) {
    int idx = blockIdx.x * 256 + threadIdx.x;       // over NROWS*NHEADS
    if (idx >= NROWS * NHEADS) return;
    int h  = idx & (NHEADS - 1);
    int bl = idx >> 5;
    float u = zx[(size_t)bl * D_IN_PROJ + D_INNER + CONV_DIM + h] + dt_bias[h];
    float d = (u > 20.f) ? u : log1pf(expf(u));
    dt[idx] = d;
    dA[idx] = expf(-expf(A_log[h]) * d);
}

// ---------------- K3: sequential SSM scan ----------------
// grid = B * NHEADS * 2 (p-chunks of 32); 256 threads.
// thread t: p_loc = t>>3 (0..31), nseg = t&7 -> 16 states n0=nseg*16..+15.
__global__ __launch_bounds__(256) void ssm_scan(const float* __restrict__ xBC,
                                                const float* __restrict__ dt,
                                                const float* __restrict__ dA,
                                                const float* __restrict__ Dp,
                                                float* __restrict__ y) {
    int blk  = blockIdx.x;          // 0..255
    int pch  = blk & 1;
    int h    = (blk >> 1) & (NHEADS - 1);
    int b    = blk >> 6;

    int t     = threadIdx.x;
    int p_loc = t >> 3;
    int nseg  = t & 7;
    int n0    = nseg * 16;
    int p     = pch * 32 + p_loc;

    float hs[16];
    #pragma unroll
    for (int i = 0; i < 16; ++i) hs[i] = 0.f;

    float Dh = Dp[h];
    const float* xbase = xBC + (size_t)b * SEQ * CONV_DIM;

    for (int l = 0; l < SEQ; ++l) {
        const float* row = xbase + (size_t)l * CONV_DIM;
        int bl = b * SEQ + l;
        float xv  = row[h * HEADDIM + p];
        float dtv = dt[bl * NHEADS + h];
        float dAv = dA[bl * NHEADS + h];
        float dtx = dtv * xv;

        const float4* Bv = (const float4*)(row + D_INNER + n0);
        const float4* Cv = (const float4*)(row + D_INNER + DSTATE + n0);

        float partial = 0.f;
        #pragma unroll
        for (int j = 0; j < 4; ++j) {
            float4 bb = Bv[j];
            float4 cc = Cv[j];
            float* hp = hs + j * 4;
            hp[0] = fmaf(dAv, hp[0], dtx * bb.x); partial = fmaf(hp[0], cc.x, partial);
            hp[1] = fmaf(dAv, hp[1], dtx * bb.y); partial = fmaf(hp[1], cc.y, partial);
            hp[2] = fmaf(dAv, hp[2], dtx * bb.z); partial = fmaf(hp[2], cc.z, partial);
            hp[3] = fmaf(dAv, hp[3], dtx * bb.w); partial = fmaf(hp[3], cc.w, partial);
        }
        partial += __shfl_xor(partial, 1);
        partial += __shfl_xor(partial, 2);
        partial += __shfl_xor(partial, 4);

        if (nseg == 0)
            y[(size_t)bl * D_INNER + h * HEADDIM + p] = fmaf(Dh, xv, partial);
    }
}

// ---------------- K4: yz = y*silu(z); RMSNorm(yz)*norm_w ----------------
// one block (256 thr) per row of 2048
__global__ __launch_bounds__(256) void gate_rmsnorm(const float* __restrict__ y,
                                                    const float* __restrict__ zx,
                                                    const float* __restrict__ nw,
                                                    float* __restrict__ out) {
    int bl = blockIdx.x;
    const float* yr = y + (size_t)bl * D_INNER;
    const float* zr = zx + (size_t)bl * D_IN_PROJ;   // z = first 2048 cols
    int e0 = threadIdx.x * 8;

    float4 y0 = *(const float4*)(yr + e0);
    float4 y1 = *(const float4*)(yr + e0 + 4);
    float4 z0 = *(const float4*)(zr + e0);
    float4 z1 = *(const float4*)(zr + e0 + 4);

    float v[8];
    float zz[8] = {z0.x, z0.y, z0.z, z0.w, z1.x, z1.y, z1.z, z1.w};
    float yy[8] = {y0.x, y0.y, y0.z, y0.w, y1.x, y1.y, y1.z, y1.w};
    float ss = 0.f;
    #pragma unroll
    for (int i = 0; i < 8; ++i) {
        v[i] = yy[i] * zz[i] * sigmoidf_(zz[i]);
        ss = fmaf(v[i], v[i], ss);
    }
    // wave reduce (64 lanes)
    ss += __shfl_xor(ss, 1);  ss += __shfl_xor(ss, 2);  ss += __shfl_xor(ss, 4);
    ss += __shfl_xor(ss, 8);  ss += __shfl_xor(ss, 16); ss += __shfl_xor(ss, 32);
    __shared__ float red[4];
    int wave = threadIdx.x >> 6;
    if ((threadIdx.x & 63) == 0) red[wave] = ss;
    __syncthreads();
    ss = red[0] + red[1] + red[2] + red[3];

    float scale = rsqrtf(ss * (1.f / D_INNER) + EPSF);
    float* orow = out + (size_t)bl * D_INNER;
    #pragma unroll
    for (int i = 0; i < 8; ++i) orow[e0 + i] = v[i] * scale * nw[e0 + i];
}

// ---------------- launcher ----------------
extern "C" void kernel_launch(void* const* d_in, const int* in_sizes, int n_in,
                              void* d_out, int out_size, void* d_ws, size_t ws_size,
                              hipStream_t stream) {
    const float* x        = (const float*)d_in[0];
    const float* in_w     = (const float*)d_in[1];
    const float* conv_w   = (const float*)d_in[2];
    const float* conv_b   = (const float*)d_in[3];
    const float* dt_bias  = (const float*)d_in[4];
    const float* A_log    = (const float*)d_in[5];
    const float* Dp       = (const float*)d_in[6];
    const float* norm_w   = (const float*)d_in[7];
    const float* out_w    = (const float*)d_in[8];
    float* out            = (float*)d_out;   // reference output dtype is float32

    float* ws   = (float*)d_ws;
    float* zx   = ws + OFF_ZX;
    float* xBC  = ws + OFF_XBC;
    float* dt   = ws + OFF_DT;
    float* dA   = ws + OFF_DA;
    float* y    = ws + OFF_Y;

    // K1: zxbcdt = x @ in_proj_w^T   (4096 x 4384 x 1024)
    {
        dim3 grid((D_IN_PROJ + 63) / 64, NROWS / 64);
        gemm_tn<<<grid, 256, 0, stream>>>(x, in_w, zx, NROWS, D_IN_PROJ, DM);
    }
    // K2: conv + silu
    {
        int total = NROWS * CONV_DIM;
        conv_silu<<<(total + 255) / 256, 256, 0, stream>>>(zx, conv_w, conv_b, xBC);
    }
    // K2b: dt / dA
    {
        int total = NROWS * NHEADS;
        dt_da<<<(total + 255) / 256, 256, 0, stream>>>(zx, dt_bias, A_log, dt, dA);
    }
    // K3: scan
    ssm_scan<<<BATCH * NHEADS * 2, 256, 0, stream>>>(xBC, dt, dA, Dp, y);
    // K4: gate + rmsnorm (in-place over y)
    gate_rmsnorm<<<NROWS, 256, 0, stream>>>(y, zx, norm_w, y);
    // K5: out = yz @ out_proj_w^T  (4096 x 1024 x 2048), fp32 store
    {
        dim3 grid(DM / 64, NROWS / 64);
        gemm_tn<<<grid, 256, 0, stream>>>(y, out_w, out, NROWS, DM, D_INNER);
    }
}

// Round 4
// 779.976 us; speedup vs baseline: 2.0119x; 2.0119x over previous
//
#include <hip/hip_runtime.h>
#include <hip/hip_bf16.h>

#define DM        1024
#define D_INNER   2048
#define NHEADS    32
#define HEADDIM   64
#define DSTATE    128
#define DCONV     4
#define CONV_DIM  (D_INNER + 2*DSTATE)            // 2304
#define D_IN_PROJ (2*D_INNER + 2*DSTATE + NHEADS) // 4384
#define NPAD_IN   4480                            // 35*128, padded N for K1
#define BATCH     4
#define SEQ       1024
#define NROWS     (BATCH*SEQ)                     // 4096
#define EPSF      1e-5f

// ---------------- workspace layout ----------------
// float region
#define OFF_ZX   ((size_t)0)                        // [4096][4384]  zxbcdt fp32
#define OFF_XBC  ((size_t)(NROWS)*D_IN_PROJ)        // [4096][2304]
#define OFF_DT   (OFF_XBC + (size_t)NROWS*CONV_DIM) // [4096][32]
#define OFF_DA   (OFF_DT  + (size_t)NROWS*NHEADS)   // [4096][32]
#define OFF_Y    (OFF_DA  + (size_t)NROWS*NHEADS)   // [4096][2048] fp32
#define FLOAT_END (OFF_Y + (size_t)NROWS*D_INNER)
// bf16 (short) region, offsets in shorts from (short*)(ws + FLOAT_END)
#define SOFF_XB   ((size_t)0)                           // [4096][1024]
#define SOFF_W1B  (SOFF_XB  + (size_t)NROWS*DM)         // [4480][1024] padded
#define SOFF_W2B  (SOFF_W1B + (size_t)NPAD_IN*DM)       // [1024][2048]
#define SOFF_YZB  (SOFF_W2B + (size_t)DM*D_INNER)       // [4096][2048]

typedef float  vf4   __attribute__((ext_vector_type(4)));
typedef short  s16x8 __attribute__((ext_vector_type(8)));
typedef short  s16x4 __attribute__((ext_vector_type(4)));
typedef __bf16 bf16x8 __attribute__((ext_vector_type(8)));

__device__ __forceinline__ float sigmoidf_(float x) { return 1.f / (1.f + expf(-x)); }

__device__ __forceinline__ short f2bf(float f) {
    unsigned u = __builtin_bit_cast(unsigned, f);
    u += 0x7fffu + ((u >> 16) & 1u);          // RNE
    return (short)(u >> 16);
}
__device__ __forceinline__ bf16x8 as_bf(s16x8 v) { return __builtin_bit_cast(bf16x8, v); }

__device__ __forceinline__ void gload16(const short* g, short* l) {
    __builtin_amdgcn_global_load_lds(
        (const __attribute__((address_space(1))) unsigned int*)g,
        (__attribute__((address_space(3))) unsigned int*)l, 16, 0, 0);
}

// ---------------- K0: fp32 -> bf16 convert (optionally zero-padded tail) ----
__global__ __launch_bounds__(256) void cvt_bf16(const float* __restrict__ src,
                                                short* __restrict__ dst,
                                                int n_src, int n_dst) {
    int i = (blockIdx.x * 256 + threadIdx.x) * 4;
    if (i >= n_dst) return;
    s16x4 o;
    if (i + 3 < n_src) {
        float4 v = *(const float4*)(src + i);
        o[0] = f2bf(v.x); o[1] = f2bf(v.y); o[2] = f2bf(v.z); o[3] = f2bf(v.w);
    } else {
        #pragma unroll
        for (int j = 0; j < 4; ++j) o[j] = (i + j < n_src) ? f2bf(src[i + j]) : (short)0;
    }
    *(s16x4*)(dst + i) = o;
}

// ---------------- MFMA GEMM: C[M][Nout] = A[M][K] * B[Npad][K]^T ------------
// 128x128 tile, BK=64, 4 waves (2x2), 16x16x32 bf16 MFMA, 4x4 frags/wave.
// LDS XOR-swizzle: chunk (r,c) stored at slot r*8 + (c ^ (r&7)); staging
// pre-swizzles the GLOBAL source chunk so global_load_lds stays linear (rule 21).
__global__ __launch_bounds__(256) void gemm_mfma(const short* __restrict__ A,
                                                 const short* __restrict__ B,
                                                 float* __restrict__ C,
                                                 int M, int K, int Nout) {
    __shared__ short smem[16384];               // A:[0,8192) B:[8192,16384) shorts
    const int tid = threadIdx.x;
    const int bm = blockIdx.y * 128, bn = blockIdx.x * 128;
    const int lane = tid & 63, lr = lane & 15, lg = lane >> 4;
    const int w = tid >> 6, wm = w >> 1, wn = w & 1;

    const short* ga[4]; const short* gb[4];
    short* la[4]; short* lb[4];
    #pragma unroll
    for (int t = 0; t < 4; ++t) {
        int s = t * 256 + tid;                  // slot 0..1023
        int r = s >> 3;
        int c = (s & 7) ^ (r & 7);              // pre-swizzled source chunk
        ga[t] = A + (size_t)(bm + r) * K + c * 8;
        gb[t] = B + (size_t)(bn + r) * K + c * 8;
        la[t] = &smem[s * 8];
        lb[t] = &smem[8192 + s * 8];
    }

    vf4 acc[4][4] = {};

    for (int k0 = 0; k0 < K; k0 += 64) {
        __syncthreads();                        // prev compute done reading LDS
        #pragma unroll
        for (int t = 0; t < 4; ++t) gload16(ga[t] + k0, la[t]);
        #pragma unroll
        for (int t = 0; t < 4; ++t) gload16(gb[t] + k0, lb[t]);
        __syncthreads();                        // drains vmcnt -> tiles visible
        #pragma unroll
        for (int kk = 0; kk < 2; ++kk) {
            const int co = ((kk * 4 + lg) ^ (lr & 7)) * 8;  // un-swizzle on read
            s16x8 av[4], bv[4];
            #pragma unroll
            for (int f = 0; f < 4; ++f) {
                av[f] = *(const s16x8*)&smem[(wm * 64 + f * 16 + lr) * 64 + co];
                bv[f] = *(const s16x8*)&smem[8192 + (wn * 64 + f * 16 + lr) * 64 + co];
            }
            #pragma unroll
            for (int i = 0; i < 4; ++i)
                #pragma unroll
                for (int j = 0; j < 4; ++j)
                    acc[i][j] = __builtin_amdgcn_mfma_f32_16x16x32_bf16(
                        as_bf(av[i]), as_bf(bv[j]), acc[i][j], 0, 0, 0);
        }
    }

    // C/D layout (HW-verified): col = lane&15, row = (lane>>4)*4 + reg
    #pragma unroll
    for (int i = 0; i < 4; ++i) {
        int row = bm + wm * 64 + i * 16 + lg * 4;
        #pragma unroll
        for (int j = 0; j < 4; ++j) {
            int col = bn + wn * 64 + j * 16 + lr;
            if (col < Nout) {
                float* cp = C + (size_t)row * Nout + col;
                #pragma unroll
                for (int q = 0; q < 4; ++q) cp[(size_t)q * Nout] = acc[i][j][q];
            }
        }
    }
}

// ---------------- K2: causal depthwise conv(4) + silu ----------------
__global__ __launch_bounds__(256) void conv_silu(const float* __restrict__ zx,
                                                 const float* __restrict__ cw,
                                                 const float* __restrict__ cb,
                                                 float* __restrict__ xBC) {
    int idx = blockIdx.x * 256 + threadIdx.x;
    if (idx >= NROWS * CONV_DIM) return;
    int c  = idx % CONV_DIM;
    int bl = idx / CONV_DIM;
    int b  = bl / SEQ;
    int l  = bl % SEQ;

    float w0 = cw[c*4+0], w1 = cw[c*4+1], w2 = cw[c*4+2], w3 = cw[c*4+3];
    const float* base = zx + (size_t)b * SEQ * D_IN_PROJ + D_INNER + c;

    float acc = cb[c];
    if (l >= 3) acc = fmaf(base[(size_t)(l-3) * D_IN_PROJ], w0, acc);
    if (l >= 2) acc = fmaf(base[(size_t)(l-2) * D_IN_PROJ], w1, acc);
    if (l >= 1) acc = fmaf(base[(size_t)(l-1) * D_IN_PROJ], w2, acc);
    acc = fmaf(base[(size_t)l * D_IN_PROJ], w3, acc);

    xBC[idx] = acc * sigmoidf_(acc);
}

// ---------------- K2b: dt = softplus(dt_raw + bias), dA = exp(dt*A) ---------
__global__ __launch_bounds__(256) void dt_da(const float* __restrict__ zx,
                                             const float* __restrict__ dt_bias,
                                             const float* __restrict__ A_log,
                                             float* __restrict__ dt,
                                             float* __restrict__ dA) {
    int idx = blockIdx.x * 256 + threadIdx.x;
    if (idx >= NROWS * NHEADS) return;
    int h  = idx & (NHEADS - 1);
    int bl = idx >> 5;
    float u = zx[(size_t)bl * D_IN_PROJ + D_INNER + CONV_DIM + h] + dt_bias[h];
    float d = (u > 20.f) ? u : log1pf(expf(u));
    dt[idx] = d;
    dA[idx] = expf(-expf(A_log[h]) * d);
}

// ---------------- K3: sequential SSM scan ----------------
__global__ __launch_bounds__(256) void ssm_scan(const float* __restrict__ xBC,
                                                const float* __restrict__ dt,
                                                const float* __restrict__ dA,
                                                const float* __restrict__ Dp,
                                                float* __restrict__ y) {
    int blk  = blockIdx.x;
    int pch  = blk & 1;
    int h    = (blk >> 1) & (NHEADS - 1);
    int b    = blk >> 6;

    int t     = threadIdx.x;
    int p_loc = t >> 3;
    int nseg  = t & 7;
    int n0    = nseg * 16;
    int p     = pch * 32 + p_loc;

    float hs[16];
    #pragma unroll
    for (int i = 0; i < 16; ++i) hs[i] = 0.f;

    float Dh = Dp[h];
    const float* xbase = xBC + (size_t)b * SEQ * CONV_DIM;

    for (int l = 0; l < SEQ; ++l) {
        const float* row = xbase + (size_t)l * CONV_DIM;
        int bl = b * SEQ + l;
        float xv  = row[h * HEADDIM + p];
        float dtv = dt[bl * NHEADS + h];
        float dAv = dA[bl * NHEADS + h];
        float dtx = dtv * xv;

        const float4* Bv = (const float4*)(row + D_INNER + n0);
        const float4* Cv = (const float4*)(row + D_INNER + DSTATE + n0);

        float partial = 0.f;
        #pragma unroll
        for (int j = 0; j < 4; ++j) {
            float4 bb = Bv[j];
            float4 cc = Cv[j];
            float* hp = hs + j * 4;
            hp[0] = fmaf(dAv, hp[0], dtx * bb.x); partial = fmaf(hp[0], cc.x, partial);
            hp[1] = fmaf(dAv, hp[1], dtx * bb.y); partial = fmaf(hp[1], cc.y, partial);
            hp[2] = fmaf(dAv, hp[2], dtx * bb.z); partial = fmaf(hp[2], cc.z, partial);
            hp[3] = fmaf(dAv, hp[3], dtx * bb.w); partial = fmaf(hp[3], cc.w, partial);
        }
        partial += __shfl_xor(partial, 1);
        partial += __shfl_xor(partial, 2);
        partial += __shfl_xor(partial, 4);

        if (nseg == 0)
            y[(size_t)bl * D_INNER + h * HEADDIM + p] = fmaf(Dh, xv, partial);
    }
}

// ---------------- K4: yz = y*silu(z); RMSNorm(yz)*norm_w -> bf16 ------------
__global__ __launch_bounds__(256) void gate_rmsnorm(const float* __restrict__ y,
                                                    const float* __restrict__ zx,
                                                    const float* __restrict__ nw,
                                                    short* __restrict__ yzb) {
    int bl = blockIdx.x;
    const float* yr = y + (size_t)bl * D_INNER;
    const float* zr = zx + (size_t)bl * D_IN_PROJ;   // z = first 2048 cols
    int e0 = threadIdx.x * 8;

    float4 y0 = *(const float4*)(yr + e0);
    float4 y1 = *(const float4*)(yr + e0 + 4);
    float4 z0 = *(const float4*)(zr + e0);
    float4 z1 = *(const float4*)(zr + e0 + 4);

    float v[8];
    float zz[8] = {z0.x, z0.y, z0.z, z0.w, z1.x, z1.y, z1.z, z1.w};
    float yy[8] = {y0.x, y0.y, y0.z, y0.w, y1.x, y1.y, y1.z, y1.w};
    float ss = 0.f;
    #pragma unroll
    for (int i = 0; i < 8; ++i) {
        v[i] = yy[i] * zz[i] * sigmoidf_(zz[i]);
        ss = fmaf(v[i], v[i], ss);
    }
    ss += __shfl_xor(ss, 1);  ss += __shfl_xor(ss, 2);  ss += __shfl_xor(ss, 4);
    ss += __shfl_xor(ss, 8);  ss += __shfl_xor(ss, 16); ss += __shfl_xor(ss, 32);
    __shared__ float red[4];
    int wave = threadIdx.x >> 6;
    if ((threadIdx.x & 63) == 0) red[wave] = ss;
    __syncthreads();
    ss = red[0] + red[1] + red[2] + red[3];

    float scale = rsqrtf(ss * (1.f / D_INNER) + EPSF);
    s16x8 o;
    #pragma unroll
    for (int i = 0; i < 8; ++i) o[i] = f2bf(v[i] * scale * nw[e0 + i]);
    *(s16x8*)(yzb + (size_t)bl * D_INNER + e0) = o;
}

// ---------------- launcher ----------------
extern "C" void kernel_launch(void* const* d_in, const int* in_sizes, int n_in,
                              void* d_out, int out_size, void* d_ws, size_t ws_size,
                              hipStream_t stream) {
    const float* x        = (const float*)d_in[0];
    const float* in_w     = (const float*)d_in[1];
    const float* conv_w   = (const float*)d_in[2];
    const float* conv_b   = (const float*)d_in[3];
    const float* dt_bias  = (const float*)d_in[4];
    const float* A_log    = (const float*)d_in[5];
    const float* Dp       = (const float*)d_in[6];
    const float* norm_w   = (const float*)d_in[7];
    const float* out_w    = (const float*)d_in[8];
    float* out            = (float*)d_out;           // fp32 output

    float* ws   = (float*)d_ws;
    float* zx   = ws + OFF_ZX;
    float* xBC  = ws + OFF_XBC;
    float* dt   = ws + OFF_DT;
    float* dA   = ws + OFF_DA;
    float* y    = ws + OFF_Y;
    short* sb   = (short*)(ws + FLOAT_END);
    short* xb   = sb + SOFF_XB;
    short* w1b  = sb + SOFF_W1B;
    short* w2b  = sb + SOFF_W2B;
    short* yzb  = sb + SOFF_YZB;

    // K0: fp32 -> bf16 conversions
    {
        int n = NROWS * DM;
        cvt_bf16<<<n / 4 / 256, 256, 0, stream>>>(x, xb, n, n);
        int ns = D_IN_PROJ * DM, nd = NPAD_IN * DM;
        cvt_bf16<<<nd / 4 / 256, 256, 0, stream>>>(in_w, w1b, ns, nd);
        int n2 = DM * D_INNER;
        cvt_bf16<<<n2 / 4 / 256, 256, 0, stream>>>(out_w, w2b, n2, n2);
    }
    // K1: zxbcdt = x @ in_proj_w^T  (4096 x 4384 x 1024), MFMA bf16
    {
        dim3 grid(NPAD_IN / 128, NROWS / 128);
        gemm_mfma<<<grid, 256, 0, stream>>>(xb, w1b, zx, NROWS, DM, D_IN_PROJ);
    }
    // K2: conv + silu
    {
        int total = NROWS * CONV_DIM;
        conv_silu<<<(total + 255) / 256, 256, 0, stream>>>(zx, conv_w, conv_b, xBC);
    }
    // K2b: dt / dA
    {
        int total = NROWS * NHEADS;
        dt_da<<<(total + 255) / 256, 256, 0, stream>>>(zx, dt_bias, A_log, dt, dA);
    }
    // K3: scan
    ssm_scan<<<BATCH * NHEADS * 2, 256, 0, stream>>>(xBC, dt, dA, Dp, y);
    // K4: gate + rmsnorm -> bf16
    gate_rmsnorm<<<NROWS, 256, 0, stream>>>(y, zx, norm_w, yzb);
    // K5: out = yz @ out_proj_w^T  (4096 x 1024 x 2048), MFMA bf16
    {
        dim3 grid(DM / 128, NROWS / 128);
        gemm_mfma<<<grid, 256, 0, stream>>>(yzb, w2b, out, NROWS, D_INNER, DM);
    }
}

// Round 5
// 726.100 us; speedup vs baseline: 2.1612x; 1.0742x over previous
//
#include <hip/hip_runtime.h>
#include <hip/hip_bf16.h>

#define DM        1024
#define D_INNER   2048
#define NHEADS    32
#define HEADDIM   64
#define DSTATE    128
#define DCONV     4
#define CONV_DIM  (D_INNER + 2*DSTATE)            // 2304
#define D_IN_PROJ (2*D_INNER + 2*DSTATE + NHEADS) // 4384
#define NPAD_IN   4480                            // 35*128, padded N for K1
#define BATCH     4
#define SEQ       1024
#define NROWS     (BATCH*SEQ)                     // 4096
#define EPSF      1e-5f

// ---------------- workspace layout ----------------
// float region
#define OFF_ZX   ((size_t)0)                        // [4096][4384]  zxbcdt fp32
#define OFF_XBC  ((size_t)(NROWS)*D_IN_PROJ)        // [4096][2304]
#define OFF_DT   (OFF_XBC + (size_t)NROWS*CONV_DIM) // [4096][32]
#define OFF_DA   (OFF_DT  + (size_t)NROWS*NHEADS)   // [4096][32]
#define OFF_Y    (OFF_DA  + (size_t)NROWS*NHEADS)   // [4096][2048] fp32
#define FLOAT_END (OFF_Y + (size_t)NROWS*D_INNER)
// bf16 (short) region, offsets in shorts from (short*)(ws + FLOAT_END)
#define SOFF_XB   ((size_t)0)                           // [4096][1024]
#define SOFF_W1B  (SOFF_XB  + (size_t)NROWS*DM)         // [4480][1024] padded
#define SOFF_W2B  (SOFF_W1B + (size_t)NPAD_IN*DM)       // [1024][2048]
#define SOFF_YZB  (SOFF_W2B + (size_t)DM*D_INNER)       // [4096][2048]

typedef float  vf4   __attribute__((ext_vector_type(4)));
typedef short  s16x8 __attribute__((ext_vector_type(8)));
typedef short  s16x4 __attribute__((ext_vector_type(4)));
typedef __bf16 bf16x8 __attribute__((ext_vector_type(8)));

__device__ __forceinline__ float sigmoidf_(float x) { return 1.f / (1.f + expf(-x)); }

__device__ __forceinline__ short f2bf(float f) {
    unsigned u = __builtin_bit_cast(unsigned, f);
    u += 0x7fffu + ((u >> 16) & 1u);          // RNE
    return (short)(u >> 16);
}
__device__ __forceinline__ bf16x8 as_bf(s16x8 v) { return __builtin_bit_cast(bf16x8, v); }

__device__ __forceinline__ void gload16(const short* g, short* l) {
    __builtin_amdgcn_global_load_lds(
        (const __attribute__((address_space(1))) unsigned int*)g,
        (__attribute__((address_space(3))) unsigned int*)l, 16, 0, 0);
}

// ---------------- K0: fp32 -> bf16 convert (optionally zero-padded tail) ----
__global__ __launch_bounds__(256) void cvt_bf16(const float* __restrict__ src,
                                                short* __restrict__ dst,
                                                int n_src, int n_dst) {
    int i = (blockIdx.x * 256 + threadIdx.x) * 4;
    if (i >= n_dst) return;
    s16x4 o;
    if (i + 3 < n_src) {
        float4 v = *(const float4*)(src + i);
        o[0] = f2bf(v.x); o[1] = f2bf(v.y); o[2] = f2bf(v.z); o[3] = f2bf(v.w);
    } else {
        #pragma unroll
        for (int j = 0; j < 4; ++j) o[j] = (i + j < n_src) ? f2bf(src[i + j]) : (short)0;
    }
    *(s16x4*)(dst + i) = o;
}

// ---------------- MFMA GEMM: C[M][Nout] = A[M][K] * B[Npad][K]^T ------------
// 128x128 tile, BK=64, 4 waves (2x2), 16x16x32 bf16 MFMA, 4x4 frags/wave.
__global__ __launch_bounds__(256) void gemm_mfma(const short* __restrict__ A,
                                                 const short* __restrict__ B,
                                                 float* __restrict__ C,
                                                 int M, int K, int Nout) {
    __shared__ short smem[16384];               // A:[0,8192) B:[8192,16384) shorts
    const int tid = threadIdx.x;
    const int bm = blockIdx.y * 128, bn = blockIdx.x * 128;
    const int lane = tid & 63, lr = lane & 15, lg = lane >> 4;
    const int w = tid >> 6, wm = w >> 1, wn = w & 1;

    const short* ga[4]; const short* gb[4];
    short* la[4]; short* lb[4];
    #pragma unroll
    for (int t = 0; t < 4; ++t) {
        int s = t * 256 + tid;                  // slot 0..1023
        int r = s >> 3;
        int c = (s & 7) ^ (r & 7);              // pre-swizzled source chunk
        ga[t] = A + (size_t)(bm + r) * K + c * 8;
        gb[t] = B + (size_t)(bn + r) * K + c * 8;
        la[t] = &smem[s * 8];
        lb[t] = &smem[8192 + s * 8];
    }

    vf4 acc[4][4] = {};

    for (int k0 = 0; k0 < K; k0 += 64) {
        __syncthreads();                        // prev compute done reading LDS
        #pragma unroll
        for (int t = 0; t < 4; ++t) gload16(ga[t] + k0, la[t]);
        #pragma unroll
        for (int t = 0; t < 4; ++t) gload16(gb[t] + k0, lb[t]);
        __syncthreads();                        // drains vmcnt -> tiles visible
        #pragma unroll
        for (int kk = 0; kk < 2; ++kk) {
            const int co = ((kk * 4 + lg) ^ (lr & 7)) * 8;  // un-swizzle on read
            s16x8 av[4], bv[4];
            #pragma unroll
            for (int f = 0; f < 4; ++f) {
                av[f] = *(const s16x8*)&smem[(wm * 64 + f * 16 + lr) * 64 + co];
                bv[f] = *(const s16x8*)&smem[8192 + (wn * 64 + f * 16 + lr) * 64 + co];
            }
            #pragma unroll
            for (int i = 0; i < 4; ++i)
                #pragma unroll
                for (int j = 0; j < 4; ++j)
                    acc[i][j] = __builtin_amdgcn_mfma_f32_16x16x32_bf16(
                        as_bf(av[i]), as_bf(bv[j]), acc[i][j], 0, 0, 0);
        }
    }

    // C/D layout (HW-verified): col = lane&15, row = (lane>>4)*4 + reg
    #pragma unroll
    for (int i = 0; i < 4; ++i) {
        int row = bm + wm * 64 + i * 16 + lg * 4;
        #pragma unroll
        for (int j = 0; j < 4; ++j) {
            int col = bn + wn * 64 + j * 16 + lr;
            if (col < Nout) {
                float* cp = C + (size_t)row * Nout + col;
                #pragma unroll
                for (int q = 0; q < 4; ++q) cp[(size_t)q * Nout] = acc[i][j][q];
            }
        }
    }
}

// ---------------- K2: causal depthwise conv(4) + silu ----------------
__global__ __launch_bounds__(256) void conv_silu(const float* __restrict__ zx,
                                                 const float* __restrict__ cw,
                                                 const float* __restrict__ cb,
                                                 float* __restrict__ xBC) {
    int idx = blockIdx.x * 256 + threadIdx.x;
    if (idx >= NROWS * CONV_DIM) return;
    int c  = idx % CONV_DIM;
    int bl = idx / CONV_DIM;
    int b  = bl / SEQ;
    int l  = bl % SEQ;

    float w0 = cw[c*4+0], w1 = cw[c*4+1], w2 = cw[c*4+2], w3 = cw[c*4+3];
    const float* base = zx + (size_t)b * SEQ * D_IN_PROJ + D_INNER + c;

    float acc = cb[c];
    if (l >= 3) acc = fmaf(base[(size_t)(l-3) * D_IN_PROJ], w0, acc);
    if (l >= 2) acc = fmaf(base[(size_t)(l-2) * D_IN_PROJ], w1, acc);
    if (l >= 1) acc = fmaf(base[(size_t)(l-1) * D_IN_PROJ], w2, acc);
    acc = fmaf(base[(size_t)l * D_IN_PROJ], w3, acc);

    xBC[idx] = acc * sigmoidf_(acc);
}

// ---------------- K2b: dt = softplus(dt_raw + bias), dA = exp(dt*A) ---------
__global__ __launch_bounds__(256) void dt_da(const float* __restrict__ zx,
                                             const float* __restrict__ dt_bias,
                                             const float* __restrict__ A_log,
                                             float* __restrict__ dt,
                                             float* __restrict__ dA) {
    int idx = blockIdx.x * 256 + threadIdx.x;
    if (idx >= NROWS * NHEADS) return;
    int h  = idx & (NHEADS - 1);
    int bl = idx >> 5;
    float u = zx[(size_t)bl * D_IN_PROJ + D_INNER + CONV_DIM + h] + dt_bias[h];
    float d = (u > 20.f) ? u : log1pf(expf(u));
    dt[idx] = d;
    dA[idx] = expf(-expf(A_log[h]) * d);
}

// ---------------- K3: software-pipelined SSM scan ----------------
// grid = B*NHEADS*2 = 256 blocks, 512 threads (8 waves/CU).
// thread: p_loc = tid>>4 (0..31), nseg = tid&15 -> 8 states n0=nseg*8.
// Ping-pong prefetch: issue step l+1 loads before computing step l.
struct ScanVals { float4 b0, b1, c0, c1; float xv, dtv, dAv; };

__device__ __forceinline__ void scan_load(const float* __restrict__ row,
                                          const float* __restrict__ dtp,
                                          const float* __restrict__ dAp,
                                          int hoff, int n0, ScanVals& v) {
    v.b0 = *(const float4*)(row + D_INNER + n0);
    v.b1 = *(const float4*)(row + D_INNER + n0 + 4);
    v.c0 = *(const float4*)(row + D_INNER + DSTATE + n0);
    v.c1 = *(const float4*)(row + D_INNER + DSTATE + n0 + 4);
    v.xv  = row[hoff];
    v.dtv = *dtp;
    v.dAv = *dAp;
}

__global__ __launch_bounds__(512) void ssm_scan(const float* __restrict__ xBC,
                                                const float* __restrict__ dt,
                                                const float* __restrict__ dA,
                                                const float* __restrict__ Dp,
                                                float* __restrict__ y) {
    int blk  = blockIdx.x;          // 0..255
    int pch  = blk & 1;
    int h    = (blk >> 1) & (NHEADS - 1);
    int b    = blk >> 6;

    int t     = threadIdx.x;
    int p_loc = t >> 4;             // 0..31
    int nseg  = t & 15;             // 0..15
    int n0    = nseg * 8;
    int p     = pch * 32 + p_loc;
    int hoff  = h * HEADDIM + p;

    float hs[8];
    #pragma unroll
    for (int i = 0; i < 8; ++i) hs[i] = 0.f;

    float Dh = Dp[h];
    const float* xbase = xBC + (size_t)b * SEQ * CONV_DIM;
    const float* dtb   = dt + (size_t)b * SEQ * NHEADS + h;
    const float* dAb   = dA + (size_t)b * SEQ * NHEADS + h;
    float*       yb    = y + (size_t)b * SEQ * D_INNER + hoff;

    ScanVals vA, vB;
    scan_load(xbase, dtb, dAb, hoff, n0, vA);

    #define SCAN_STEP(V, L)                                                        \
    {                                                                              \
        float dtx = V.dtv * V.xv;                                                  \
        float partial = 0.f;                                                       \
        hs[0] = fmaf(V.dAv, hs[0], dtx * V.b0.x); partial = fmaf(hs[0], V.c0.x, partial); \
        hs[1] = fmaf(V.dAv, hs[1], dtx * V.b0.y); partial = fmaf(hs[1], V.c0.y, partial); \
        hs[2] = fmaf(V.dAv, hs[2], dtx * V.b0.z); partial = fmaf(hs[2], V.c0.z, partial); \
        hs[3] = fmaf(V.dAv, hs[3], dtx * V.b0.w); partial = fmaf(hs[3], V.c0.w, partial); \
        hs[4] = fmaf(V.dAv, hs[4], dtx * V.b1.x); partial = fmaf(hs[4], V.c1.x, partial); \
        hs[5] = fmaf(V.dAv, hs[5], dtx * V.b1.y); partial = fmaf(hs[5], V.c1.y, partial); \
        hs[6] = fmaf(V.dAv, hs[6], dtx * V.b1.z); partial = fmaf(hs[6], V.c1.z, partial); \
        hs[7] = fmaf(V.dAv, hs[7], dtx * V.b1.w); partial = fmaf(hs[7], V.c1.w, partial); \
        partial += __shfl_xor(partial, 1);                                         \
        partial += __shfl_xor(partial, 2);                                         \
        partial += __shfl_xor(partial, 4);                                         \
        partial += __shfl_xor(partial, 8);                                         \
        if (nseg == 0) yb[(size_t)(L) * D_INNER] = fmaf(Dh, V.xv, partial);        \
    }

    for (int l = 0; l < SEQ; l += 2) {
        int l1 = l + 1;                               // always <= SEQ-1
        scan_load(xbase + (size_t)l1 * CONV_DIM, dtb + (size_t)l1 * NHEADS,
                  dAb + (size_t)l1 * NHEADS, hoff, n0, vB);
        SCAN_STEP(vA, l);
        int l2 = (l + 2 < SEQ) ? l + 2 : SEQ - 1;     // redundant tail load, harmless
        scan_load(xbase + (size_t)l2 * CONV_DIM, dtb + (size_t)l2 * NHEADS,
                  dAb + (size_t)l2 * NHEADS, hoff, n0, vA);
        SCAN_STEP(vB, l1);
    }
    #undef SCAN_STEP
}

// ---------------- K4: yz = y*silu(z); RMSNorm(yz)*norm_w -> bf16 ------------
__global__ __launch_bounds__(256) void gate_rmsnorm(const float* __restrict__ y,
                                                    const float* __restrict__ zx,
                                                    const float* __restrict__ nw,
                                                    short* __restrict__ yzb) {
    int bl = blockIdx.x;
    const float* yr = y + (size_t)bl * D_INNER;
    const float* zr = zx + (size_t)bl * D_IN_PROJ;   // z = first 2048 cols
    int e0 = threadIdx.x * 8;

    float4 y0 = *(const float4*)(yr + e0);
    float4 y1 = *(const float4*)(yr + e0 + 4);
    float4 z0 = *(const float4*)(zr + e0);
    float4 z1 = *(const float4*)(zr + e0 + 4);

    float v[8];
    float zz[8] = {z0.x, z0.y, z0.z, z0.w, z1.x, z1.y, z1.z, z1.w};
    float yy[8] = {y0.x, y0.y, y0.z, y0.w, y1.x, y1.y, y1.z, y1.w};
    float ss = 0.f;
    #pragma unroll
    for (int i = 0; i < 8; ++i) {
        v[i] = yy[i] * zz[i] * sigmoidf_(zz[i]);
        ss = fmaf(v[i], v[i], ss);
    }
    ss += __shfl_xor(ss, 1);  ss += __shfl_xor(ss, 2);  ss += __shfl_xor(ss, 4);
    ss += __shfl_xor(ss, 8);  ss += __shfl_xor(ss, 16); ss += __shfl_xor(ss, 32);
    __shared__ float red[4];
    int wave = threadIdx.x >> 6;
    if ((threadIdx.x & 63) == 0) red[wave] = ss;
    __syncthreads();
    ss = red[0] + red[1] + red[2] + red[3];

    float scale = rsqrtf(ss * (1.f / D_INNER) + EPSF);
    s16x8 o;
    #pragma unroll
    for (int i = 0; i < 8; ++i) o[i] = f2bf(v[i] * scale * nw[e0 + i]);
    *(s16x8*)(yzb + (size_t)bl * D_INNER + e0) = o;
}

// ---------------- launcher ----------------
extern "C" void kernel_launch(void* const* d_in, const int* in_sizes, int n_in,
                              void* d_out, int out_size, void* d_ws, size_t ws_size,
                              hipStream_t stream) {
    const float* x        = (const float*)d_in[0];
    const float* in_w     = (const float*)d_in[1];
    const float* conv_w   = (const float*)d_in[2];
    const float* conv_b   = (const float*)d_in[3];
    const float* dt_bias  = (const float*)d_in[4];
    const float* A_log    = (const float*)d_in[5];
    const float* Dp       = (const float*)d_in[6];
    const float* norm_w   = (const float*)d_in[7];
    const float* out_w    = (const float*)d_in[8];
    float* out            = (float*)d_out;           // fp32 output

    float* ws   = (float*)d_ws;
    float* zx   = ws + OFF_ZX;
    float* xBC  = ws + OFF_XBC;
    float* dt   = ws + OFF_DT;
    float* dA   = ws + OFF_DA;
    float* y    = ws + OFF_Y;
    short* sb   = (short*)(ws + FLOAT_END);
    short* xb   = sb + SOFF_XB;
    short* w1b  = sb + SOFF_W1B;
    short* w2b  = sb + SOFF_W2B;
    short* yzb  = sb + SOFF_YZB;

    // K0: fp32 -> bf16 conversions
    {
        int n = NROWS * DM;
        cvt_bf16<<<n / 4 / 256, 256, 0, stream>>>(x, xb, n, n);
        int ns = D_IN_PROJ * DM, nd = NPAD_IN * DM;
        cvt_bf16<<<nd / 4 / 256, 256, 0, stream>>>(in_w, w1b, ns, nd);
        int n2 = DM * D_INNER;
        cvt_bf16<<<n2 / 4 / 256, 256, 0, stream>>>(out_w, w2b, n2, n2);
    }
    // K1: zxbcdt = x @ in_proj_w^T  (4096 x 4384 x 1024), MFMA bf16
    {
        dim3 grid(NPAD_IN / 128, NROWS / 128);
        gemm_mfma<<<grid, 256, 0, stream>>>(xb, w1b, zx, NROWS, DM, D_IN_PROJ);
    }
    // K2: conv + silu
    {
        int total = NROWS * CONV_DIM;
        conv_silu<<<(total + 255) / 256, 256, 0, stream>>>(zx, conv_w, conv_b, xBC);
    }
    // K2b: dt / dA
    {
        int total = NROWS * NHEADS;
        dt_da<<<(total + 255) / 256, 256, 0, stream>>>(zx, dt_bias, A_log, dt, dA);
    }
    // K3: scan (512 threads, ping-pong prefetch)
    ssm_scan<<<BATCH * NHEADS * 2, 512, 0, stream>>>(xBC, dt, dA, Dp, y);
    // K4: gate + rmsnorm -> bf16
    gate_rmsnorm<<<NROWS, 256, 0, stream>>>(y, zx, norm_w, yzb);
    // K5: out = yz @ out_proj_w^T  (4096 x 1024 x 2048), MFMA bf16
    {
        dim3 grid(DM / 128, NROWS / 128);
        gemm_mfma<<<grid, 256, 0, stream>>>(yzb, w2b, out, NROWS, D_INNER, DM);
    }
}